// Round 1
// baseline (268.783 us; speedup 1.0000x reference)
//
#include <hip/hip_runtime.h>
#include <hip/hip_bf16.h>
#include <cstdint>
#include <cstddef>

namespace {

constexpr int BATCH = 16;
constexpr int LEN   = 8192;
constexpr int CIN   = 257;
constexpr int CS    = 256;   // space channels
constexpr int NF    = 4096;  // output frames
constexpr int KG    = 1280;  // GEMM K (5 taps * 256 ch), time handled as rank-1
constexpr int MT    = 128;   // frames per block
constexpr int NITER = 20;    // K iterations of 64

// workspace layout: only bf16 W transpose + w0 column. ~0.66 MB.
constexpr size_t WT_BYTES = (size_t)CS * KG * 2;      // 655,360
constexpr size_t W0_OFF   = WT_BYTES;
constexpr size_t WS_NEED  = W0_OFF + (size_t)CS * 4;  // ~656.4 KB

typedef __attribute__((ext_vector_type(8))) short short8;
typedef __attribute__((ext_vector_type(8))) unsigned short ushort8v;
typedef __attribute__((ext_vector_type(4))) float f32x4;

__device__ __forceinline__ unsigned short f2bf_bits(float f) {
  union { __hip_bfloat16 h; unsigned short u; } cv;
  cv.h = __float2bfloat16(f);
  return cv.u;
}

__device__ __forceinline__ void async_cp16(const void* g, void* l) {
  __builtin_amdgcn_global_load_lds(
      (const __attribute__((address_space(1))) void*)g,
      (__attribute__((address_space(3))) void*)l,
      16, 0, 0);
}

} // namespace

// ---------------- prep: W (257x1281 f32) -> wt bf16 [256][1280] + w0[256] f32
__global__ void prep_w_kernel(const float* __restrict__ W,
                              __hip_bfloat16* __restrict__ wt,
                              float* __restrict__ w0) {
  int n = blockIdx.x;                    // 0..255 -> out channel n+1
  const float* wrow = W + (size_t)(n + 1) * 1281;
  for (int k = threadIdx.x; k < KG; k += blockDim.x)
    wt[(size_t)n * KG + k] = __float2bfloat16(wrow[1 + k]);
  if (threadIdx.x == 0) w0[n] = wrow[0];
}

// ---------------- fused GEMM: [128 frames] x [256 out ch], K=1280, bf16 MFMA
// A is staged straight from f32 x (in-register cvt to bf16 + per-frame sumsq);
// B via global_load_lds from prepped wt. Double-buffered LDS, counted vmcnt
// (raw s_barrier, never vmcnt(0) in steady state).
// block: 512 threads = 8 waves; wave (mh = w>>2, nq = w&3) computes 64x64.
__global__ __launch_bounds__(512, 2) void lorentz_fused_kernel(
    const float* __restrict__ x,
    const __hip_bfloat16* __restrict__ wt,
    const float* __restrict__ w0,
    const float* __restrict__ bvec,
    float* __restrict__ out) {
  // LDS: A0/A1 = 128x64 bf16 (16KB each), B0/B1 = 256x64 bf16 (32KB each)
  __shared__ alignas(16) char lds[98304];
  __shared__ alignas(16) float time0_s[128];
  __shared__ alignas(16) float normsq_s[128];
  char* const A0 = lds;
  char* const A1 = lds + 16384;
  char* const B0 = lds + 32768;
  char* const B1 = lds + 65536;

  const int tid   = threadIdx.x;
  const int w     = tid >> 6;
  const int lane  = tid & 63;
  const int row16 = lane & 15;
  const int q     = lane >> 4;
  const int mh    = w >> 2;     // 0..1  M-half
  const int nq    = w & 3;      // 0..3  N-quarter
  const int lg    = lane >> 3;  // 0..7 row-in-group for staging
  const int lc    = lane & 7;   // chunk index for staging
  const int csw   = lc ^ lg;    // XOR swizzle (pos = chunk ^ (row&7))

  const int bx    = blockIdx.x;
  const int b     = bx >> 5;
  const int Mblk  = (bx & 31) * MT;

  const int m0 = w * 16 + lg;      // frame row, j=0
  const int m1 = m0 + 8;           // frame row, j=1
  const float* xb = x + (size_t)b * LEN * CIN;

  f32x4 acc[4][4];
#pragma unroll
  for (int i = 0; i < 4; ++i)
#pragma unroll
    for (int j = 0; j < 4; ++j) acc[i][j] = (f32x4){0.f, 0.f, 0.f, 0.f};

  float ssq0 = 0.f, ssq1 = 0.f;
  f32x4 a00, a01, a10, a11;        // in-flight A registers (8 floats per row slot)

  // ---- helpers ------------------------------------------------------------
  auto loadA = [&](int it) {
    const int kk = it >> 2;
    const int c0 = (it & 3) << 6;
    const int coff = 1 + c0 + lc * 8;
    const int t0 = 2 * (Mblk + m0) + kk - 2;
    const int t1 = t0 + 16;
    a00 = (f32x4){0.f, 0.f, 0.f, 0.f};
    a01 = a00; a10 = a00; a11 = a00;
    if ((unsigned)t0 < (unsigned)LEN) {
      const float* g = xb + (size_t)t0 * CIN + coff;
      __builtin_memcpy(&a00, g, 16);
      __builtin_memcpy(&a01, g + 4, 16);
    }
    if ((unsigned)t1 < (unsigned)LEN) {
      const float* g = xb + (size_t)t1 * CIN + coff;
      __builtin_memcpy(&a10, g, 16);
      __builtin_memcpy(&a11, g + 4, 16);
    }
  };

  auto writeA = [&](char* A) {
    ssq0 += a00[0]*a00[0] + a00[1]*a00[1] + a00[2]*a00[2] + a00[3]*a00[3]
          + a01[0]*a01[0] + a01[1]*a01[1] + a01[2]*a01[2] + a01[3]*a01[3];
    ssq1 += a10[0]*a10[0] + a10[1]*a10[1] + a10[2]*a10[2] + a10[3]*a10[3]
          + a11[0]*a11[0] + a11[1]*a11[1] + a11[2]*a11[2] + a11[3]*a11[3];
    ushort8v u0, u1;
#pragma unroll
    for (int i = 0; i < 4; ++i) {
      u0[i]     = f2bf_bits(a00[i]);
      u0[4 + i] = f2bf_bits(a01[i]);
      u1[i]     = f2bf_bits(a10[i]);
      u1[4 + i] = f2bf_bits(a11[i]);
    }
    *(ushort8v*)(A + ((m0 * 8 + csw) << 4)) = u0;
    *(ushort8v*)(A + ((m1 * 8 + csw) << 4)) = u1;
  };

  auto stageB = [&](int it, char* B) {
    const int k0 = it << 6;
#pragma unroll
    for (int j = 0; j < 4; ++j) {
      const int n = w * 32 + j * 8 + lg;
      async_cp16(wt + (size_t)n * KG + k0 + csw * 8, B + (w * 4 + j) * 1024);
    }
  };

  auto compute = [&](const char* A, const char* B) {
#pragma unroll
    for (int s = 0; s < 2; ++s) {
      const int p = (s * 4 + q) ^ lc;  // un-swizzle: pos = chunk ^ (row&7)
      short8 bfr[4];
#pragma unroll
      for (int nt = 0; nt < 4; ++nt)
        bfr[nt] = *(const short8*)(B + (((nq * 64 + nt * 16 + row16) * 8 + p) << 4));
#pragma unroll
      for (int mt = 0; mt < 4; ++mt) {
        short8 af = *(const short8*)(A + (((mh * 64 + mt * 16 + row16) * 8 + p) << 4));
#pragma unroll
        for (int nt = 0; nt < 4; ++nt)
          acc[mt][nt] = __builtin_amdgcn_mfma_f32_16x16x32_bf16(
              af, bfr[nt], acc[mt][nt], 0, 0, 0);
      }
    }
  };

  // ---- prologue: fill tile 0, preload A(1) --------------------------------
  loadA(0);
  stageB(0, B0);
  // wait all but the 4 just-issued B(0) loads -> A(0) regs ready
  asm volatile("s_waitcnt vmcnt(4)" ::: "memory");
  writeA(A0);
  loadA(1);
  asm volatile("s_waitcnt lgkmcnt(0)" ::: "memory");  // A(0) ds_writes done

  // ---- main loop: 2-deep pipeline, counted vmcnt, raw barriers ------------
  for (int it = 0; it < NITER; ++it) {
    char* Ac = (it & 1) ? A1 : A0;
    char* Bc = (it & 1) ? B1 : B0;
    if (it < NITER - 1) {
      char* An = (it & 1) ? A0 : A1;
      char* Bn = (it & 1) ? B0 : B1;
      stageB(it + 1, Bn);  // 4 newest VMEM ops; stay in flight across barrier
      // drain everything older: B(it) landed in LDS, A(it+1) regs ready
      asm volatile("s_waitcnt vmcnt(4)" ::: "memory");
      writeA(An);                       // cvt + ds_write A(it+1) (safe: dbuf)
      if (it < NITER - 2) loadA(it + 2);
    } else {
      asm volatile("s_waitcnt vmcnt(0)" ::: "memory");  // tail drain
    }
    asm volatile("" ::: "memory");
    __builtin_amdgcn_s_barrier();       // all waves: tile it fully resident
    asm volatile("" ::: "memory");
    compute(Ac, Bc);
    asm volatile("" ::: "memory");
    __builtin_amdgcn_s_barrier();       // all waves done reading tile it
    asm volatile("" ::: "memory");
  }

  // ---- epilogue: time0 (from in-register sumsq) + bias, renorm, store -----
  if (tid < 128) normsq_s[tid] = 0.0f;
  {
    float s0 = ssq0;
    s0 += __shfl_xor(s0, 1); s0 += __shfl_xor(s0, 2); s0 += __shfl_xor(s0, 4);
    float s1 = ssq1;
    s1 += __shfl_xor(s1, 1); s1 += __shfl_xor(s1, 2); s1 += __shfl_xor(s1, 4);
    if (lc == 0) {
      time0_s[m0] = sqrtf(1.0f + s0);
      time0_s[m1] = sqrtf(1.0f + s1);
    }
  }
  __syncthreads();

  float w0v[4], bv[4];
#pragma unroll
  for (int nt = 0; nt < 4; ++nt) {
    int n = nq * 64 + nt * 16 + row16;
    w0v[nt] = w0[n];
    bv[nt]  = bvec[1 + n];
  }

#pragma unroll
  for (int mt = 0; mt < 4; ++mt) {
    f32x4 t4 = *(const f32x4*)&time0_s[mh * 64 + mt * 16 + q * 4];
#pragma unroll
    for (int nt = 0; nt < 4; ++nt)
#pragma unroll
      for (int r = 0; r < 4; ++r)
        acc[mt][nt][r] = acc[mt][nt][r] + t4[r] * w0v[nt] + bv[nt];
#pragma unroll
    for (int r = 0; r < 4; ++r) {
      float ps = 0.f;
#pragma unroll
      for (int nt = 0; nt < 4; ++nt) ps += acc[mt][nt][r] * acc[mt][nt][r];
      ps += __shfl_xor(ps, 1);
      ps += __shfl_xor(ps, 2);
      ps += __shfl_xor(ps, 4);
      ps += __shfl_xor(ps, 8);
      if (row16 == 0) atomicAdd(&normsq_s[mh * 64 + mt * 16 + q * 4 + r], ps);
    }
  }
  __syncthreads();

#pragma unroll
  for (int mt = 0; mt < 4; ++mt) {
#pragma unroll
    for (int r = 0; r < 4; ++r) {
      int m = mh * 64 + mt * 16 + q * 4 + r;
      float nsq  = normsq_s[m];
      float norm = sqrtf(nsq);
      float scale = fminf(1.0f, 1000.0f / fmaxf(norm, 1e-8f));
      size_t ob = ((size_t)b * NF + Mblk + m) * 257;
#pragma unroll
      for (int nt = 0; nt < 4; ++nt) {
        int n = nq * 64 + nt * 16 + row16;
        out[ob + 1 + n] = acc[mt][nt][r] * scale;
      }
    }
  }
  if (tid < 128) {
    float nsq  = normsq_s[tid];
    float norm = sqrtf(nsq);
    float scale = fminf(1.0f, 1000.0f / fmaxf(norm, 1e-8f));
    size_t ob = ((size_t)b * NF + Mblk + tid) * 257;
    out[ob] = sqrtf(1.0f + scale * scale * nsq);
  }
}

// ---------------- safety fallback (only if ws < ~0.66 MB): naive fp32
__global__ void fallback_kernel(const float* __restrict__ x,
                                const float* __restrict__ W,
                                const float* __restrict__ bvec,
                                float* __restrict__ out) {
  int fid = blockIdx.x;
  int b = fid >> 12;
  int g = fid & (NF - 1);
  __shared__ float patch[1280];
  __shared__ float red[256];
  int tid = threadIdx.x;
  float ss = 0.f;
  for (int k = tid; k < 1280; k += 256) {
    int kk = k >> 8, c = k & 255;
    int t = 2 * g + kk - 2;
    float v = (t >= 0 && t < LEN) ? x[((size_t)b * LEN + t) * CIN + 1 + c] : 0.f;
    patch[k] = v;
    ss += v * v;
  }
  red[tid] = ss;
  __syncthreads();
  for (int off = 128; off > 0; off >>= 1) {
    if (tid < off) red[tid] += red[tid + off];
    __syncthreads();
  }
  float time0 = sqrtf(1.f + red[0]);
  __syncthreads();
  const float* wrow = W + (size_t)(tid + 1) * 1281;
  float acc = time0 * wrow[0] + bvec[tid + 1];
  for (int k = 0; k < 1280; ++k) acc += wrow[1 + k] * patch[k];
  red[tid] = acc * acc;
  __syncthreads();
  for (int off = 128; off > 0; off >>= 1) {
    if (tid < off) red[tid] += red[tid + off];
    __syncthreads();
  }
  float nsq = red[0];
  float norm = sqrtf(nsq);
  float scale = fminf(1.f, 1000.f / fmaxf(norm, 1e-8f));
  size_t ob = ((size_t)b * NF + g) * 257;
  out[ob + 1 + tid] = acc * scale;
  if (tid == 0) out[ob] = sqrtf(1.f + scale * scale * nsq);
}

extern "C" void kernel_launch(void* const* d_in, const int* in_sizes, int n_in,
                              void* d_out, int out_size, void* d_ws, size_t ws_size,
                              hipStream_t stream) {
  const float* x  = (const float*)d_in[0];
  const float* W  = (const float*)d_in[1];
  const float* bv = (const float*)d_in[2];
  float* out = (float*)d_out;

  if (ws_size >= WS_NEED) {
    char* ws = (char*)d_ws;
    __hip_bfloat16* wt = (__hip_bfloat16*)ws;
    float* w0          = (float*)(ws + W0_OFF);
    prep_w_kernel<<<256, 256, 0, stream>>>(W, wt, w0);
    lorentz_fused_kernel<<<BATCH * (NF / MT), 512, 0, stream>>>(x, wt, w0, bv, out);
  } else {
    fallback_kernel<<<BATCH * NF, 256, 0, stream>>>(x, W, bv, out);
  }
}